// Round 3
// baseline (86581.659 us; speedup 1.0000x reference)
//
#include <hip/hip_runtime.h>

#define HD 1024
#define BAT 64
#define KC 128
#define TT 512
#define II 256

typedef unsigned short u16;
typedef unsigned int u32;

__device__ __forceinline__ float bf2f(u16 v) {
    return __uint_as_float(((u32)v) << 16);
}

__device__ __forceinline__ u16 f2bf(float f) {
    u32 u = __float_as_uint(f);
    u32 lsb = (u >> 16) & 1u;
    u += 0x7FFFu + lsb;          // round-to-nearest-even
    return (u16)(u >> 16);
}

__device__ __forceinline__ void unpack8(const uint4 v, float* dst) {
    dst[0] = __uint_as_float(v.x << 16);
    dst[1] = __uint_as_float(v.x & 0xFFFF0000u);
    dst[2] = __uint_as_float(v.y << 16);
    dst[3] = __uint_as_float(v.y & 0xFFFF0000u);
    dst[4] = __uint_as_float(v.z << 16);
    dst[5] = __uint_as_float(v.z & 0xFFFF0000u);
    dst[6] = __uint_as_float(v.w << 16);
    dst[7] = __uint_as_float(v.w & 0xFFFF0000u);
}

// flag=1 if external tensors are bf16, 0 if fp32.
__global__ void detect_dtype(const u16* __restrict__ x, int* __restrict__ flag) {
    u32 u = x[(threadIdx.x & 63) * 2];
    u32 e = (u >> 7) & 0xFFu;
    bool sane = (e >= 0x60u) && (e <= 0x9Fu);
    unsigned long long m = __ballot(sane);
    if (threadIdx.x == 0) flag[0] = (__popcll(m) >= 48) ? 1 : 0;
}

// Core: 8 gate-rows per wave, lane = batch. A staged through LDS (spread
// ds_read_b128, each read feeds 32 FMAs). W read per-lane from global with a
// wave-uniform address made DIVERGENT via an opaque zero voffset -> compiler
// emits global_load (saddr+voffset+imm), pipelined with counted vmcnt, NOT
// s_load and NOT LDS broadcast. acc[8] in VGPRs; full K per wave.
__device__ __forceinline__ void gemm_acc8(
    float* acc, const void* Asrc, int a_bf,
    long long astr, long long aoff, int K,
    const char* const* wb, int w_bf, u32 voff,
    int tid, int lane, float* As)
{
    uint4 pa[4];
    const int nch = K >> 7;          // K / KC
    const int r0 = tid >> 3, g0 = tid & 7;

    // issue chunk 0 staging loads
    if (a_bf) {
        const u16* p = (const u16*)Asrc + (long long)r0 * astr + aoff + g0 * 16;
        pa[0] = *(const uint4*)p;
        pa[1] = *(const uint4*)(p + 8);
    } else {
        const float* p = (const float*)Asrc + (long long)r0 * astr + aoff + g0 * 16;
        pa[0] = *(const uint4*)p;       pa[1] = *(const uint4*)(p + 4);
        pa[2] = *(const uint4*)(p + 8); pa[3] = *(const uint4*)(p + 12);
    }

    for (int c = 0; c < nch; ++c) {
        __syncthreads();                      // previous chunk's reads done
        {
            float* d = &As[r0 * 132 + g0 * 16];
            if (a_bf) {
                unpack8(pa[0], d);
                unpack8(pa[1], d + 8);
            } else {
                *(uint4*)d        = pa[0];
                *(uint4*)(d + 4)  = pa[1];
                *(uint4*)(d + 8)  = pa[2];
                *(uint4*)(d + 12) = pa[3];
            }
        }
        __syncthreads();
        if (c + 1 < nch) {                    // prefetch next A chunk
            int k0 = (c + 1) << 7;
            if (a_bf) {
                const u16* p = (const u16*)Asrc + (long long)r0 * astr + aoff + k0 + g0 * 16;
                pa[0] = *(const uint4*)p;
                pa[1] = *(const uint4*)(p + 8);
            } else {
                const float* p = (const float*)Asrc + (long long)r0 * astr + aoff + k0 + g0 * 16;
                pa[0] = *(const uint4*)p;       pa[1] = *(const uint4*)(p + 4);
                pa[2] = *(const uint4*)(p + 8); pa[3] = *(const uint4*)(p + 12);
            }
        }

        const float* ap = &As[lane * 132];
        if (w_bf) {
            const long long wco = (long long)c * (KC * 2);
            #pragma unroll
            for (int k4 = 0; k4 < KC / 4; ++k4) {
                float4 a = *(const float4*)(ap + k4 * 4);
                #pragma unroll
                for (int r = 0; r < 8; ++r) {
                    ushort4 wv = *(const ushort4*)(wb[r] + wco + voff + (size_t)k4 * 8);
                    acc[r] = fmaf(a.x, bf2f(wv.x), acc[r]);
                    acc[r] = fmaf(a.y, bf2f(wv.y), acc[r]);
                    acc[r] = fmaf(a.z, bf2f(wv.z), acc[r]);
                    acc[r] = fmaf(a.w, bf2f(wv.w), acc[r]);
                }
            }
        } else {
            const long long wco = (long long)c * (KC * 4);
            #pragma unroll
            for (int k4 = 0; k4 < KC / 4; ++k4) {
                float4 a = *(const float4*)(ap + k4 * 4);
                #pragma unroll
                for (int r = 0; r < 8; ++r) {
                    float4 w = *(const float4*)(wb[r] + wco + voff + (size_t)k4 * 16);
                    acc[r] = fmaf(a.x, w.x, acc[r]);
                    acc[r] = fmaf(a.y, w.y, acc[r]);
                    acc[r] = fmaf(a.z, w.z, acc[r]);
                    acc[r] = fmaf(a.w, w.w, acc[r]);
                }
            }
        }
    }
}

// Skewed 3-role step kernel. grid = 192 x 512thr (8 waves). At launch n:
//   role 0 (blocks   0- 63): layer0 step n (gates = xp[n] + h1[n-1]@Whh0^T),
//                            finalize c1/h1[n]; then x-proj for step n+1 -> xp ring.
//   role 1 (blocks  64-127): p1[n-1] = h1[n-1]@Wih1^T + bih1 + bhh1.
//   role 2 (blocks 128-191): hh = h2[n-3]@Whh1^T; gates = p1[n-2] + hh;
//                            finalize c2/h2[n-2].
// Each wave owns 2 units x 4 gates = 8 rows; lane = batch. Cross-launch
// visibility via kernel-boundary release/acquire (proven in r0/r1).
__global__ __launch_bounds__(512) void lstm_mega(
    const int* __restrict__ flag, int n,
    const void* __restrict__ x,
    const void* __restrict__ Wih0, const void* __restrict__ Whh0,
    const void* __restrict__ bih0, const void* __restrict__ bhh0,
    const void* __restrict__ Wih1, const void* __restrict__ Whh1,
    const void* __restrict__ bih1, const void* __restrict__ bhh1,
    float* __restrict__ c1, float* __restrict__ c2,
    const float* __restrict__ h1_prev, float* __restrict__ h1_out,
    const float* __restrict__ h2_prev, float* __restrict__ h2_out,
    const float* __restrict__ xp_rd, float* __restrict__ xp_wr,
    const float* __restrict__ p1_rd, float* __restrict__ p1_wr)
{
    __shared__ __align__(16) float As[BAT * 132];

    const int bf   = flag[0];
    const int tid  = threadIdx.x;
    const int wv   = tid >> 6;
    const int lane = tid & 63;
    const int role = blockIdx.x >> 6;
    const int rb   = blockIdx.x & 63;
    const int uA   = rb * 16 + wv * 2;        // first of this wave's 2 units
    const int esz  = bf ? 2 : 4;

    u32 voff;
    asm volatile("v_mov_b32 %0, 0" : "=v"(voff));   // opaque divergent zero

    int rows[8];
    #pragma unroll
    for (int r = 0; r < 8; ++r) rows[r] = (r >> 1) * HD + uA + (r & 1);

    if (role == 0) {
        if (n >= 0 && n < TT) {
            const char* wb[8];
            #pragma unroll
            for (int r = 0; r < 8; ++r)
                wb[r] = (const char*)Whh0 + (size_t)rows[r] * HD * esz;
            float acc[8] = {0, 0, 0, 0, 0, 0, 0, 0};
            gemm_acc8(acc, h1_prev, 0, (long long)HD, 0ll, HD, wb, bf, voff, tid, lane, As);
            #pragma unroll
            for (int r = 0; r < 8; ++r)
                acc[r] += xp_rd[(long long)rows[r] * BAT + lane];
            #pragma unroll
            for (int uu = 0; uu < 2; ++uu) {
                float ig = 1.f / (1.f + __expf(-acc[0 + uu]));
                float fg = 1.f / (1.f + __expf(-acc[2 + uu]));
                float gg = tanhf(acc[4 + uu]);
                float og = 1.f / (1.f + __expf(-acc[6 + uu]));
                long long ci = (long long)lane * HD + uA + uu;
                float cn = fg * c1[ci] + ig * gg;
                c1[ci] = cn;
                h1_out[ci] = og * tanhf(cn);
            }
        }
        if (n + 1 < TT) {  // x-projection (+ both layer0 biases) for step n+1
            const char* wb[8];
            #pragma unroll
            for (int r = 0; r < 8; ++r)
                wb[r] = (const char*)Wih0 + (size_t)rows[r] * II * esz;
            float acc[8] = {0, 0, 0, 0, 0, 0, 0, 0};
            gemm_acc8(acc, x, bf, (long long)TT * II, (long long)(n + 1) * II, II,
                      wb, bf, voff, tid, lane, As);
            #pragma unroll
            for (int r = 0; r < 8; ++r) {
                float b0, b1;
                if (bf) { b0 = bf2f(((const u16*)bih0)[rows[r]]); b1 = bf2f(((const u16*)bhh0)[rows[r]]); }
                else    { b0 = ((const float*)bih0)[rows[r]];     b1 = ((const float*)bhh0)[rows[r]]; }
                xp_wr[(long long)rows[r] * BAT + lane] = acc[r] + b0 + b1;
            }
        }
    } else if (role == 1) {
        int s = n - 1;
        if (s >= 0 && s < TT) {
            const char* wb[8];
            #pragma unroll
            for (int r = 0; r < 8; ++r)
                wb[r] = (const char*)Wih1 + (size_t)rows[r] * HD * esz;
            float acc[8] = {0, 0, 0, 0, 0, 0, 0, 0};
            gemm_acc8(acc, h1_prev, 0, (long long)HD, 0ll, HD, wb, bf, voff, tid, lane, As);
            #pragma unroll
            for (int r = 0; r < 8; ++r) {
                float b0, b1;
                if (bf) { b0 = bf2f(((const u16*)bih1)[rows[r]]); b1 = bf2f(((const u16*)bhh1)[rows[r]]); }
                else    { b0 = ((const float*)bih1)[rows[r]];     b1 = ((const float*)bhh1)[rows[r]]; }
                p1_wr[(long long)rows[r] * BAT + lane] = acc[r] + b0 + b1;
            }
        }
    } else {
        int s = n - 2;
        if (s >= 0 && s < TT) {
            const char* wb[8];
            #pragma unroll
            for (int r = 0; r < 8; ++r)
                wb[r] = (const char*)Whh1 + (size_t)rows[r] * HD * esz;
            float acc[8] = {0, 0, 0, 0, 0, 0, 0, 0};
            gemm_acc8(acc, h2_prev, 0, (long long)HD, 0ll, HD, wb, bf, voff, tid, lane, As);
            #pragma unroll
            for (int r = 0; r < 8; ++r)
                acc[r] += p1_rd[(long long)rows[r] * BAT + lane];
            #pragma unroll
            for (int uu = 0; uu < 2; ++uu) {
                float ig = 1.f / (1.f + __expf(-acc[0 + uu]));
                float fg = 1.f / (1.f + __expf(-acc[2 + uu]));
                float gg = tanhf(acc[4 + uu]);
                float og = 1.f / (1.f + __expf(-acc[6 + uu]));
                long long ci = (long long)lane * HD + uA + uu;
                float cn = fg * c2[ci] + ig * gg;
                c2[ci] = cn;
                h2_out[ci] = og * tanhf(cn);
            }
        }
    }
}

__global__ __launch_bounds__(256) void fc_kernel(
    const int* __restrict__ flag,
    const float* __restrict__ h, const void* __restrict__ w,
    const void* __restrict__ b, void* __restrict__ out)
{
    int bf = flag[0];
    int bb = blockIdx.x;
    int o  = threadIdx.x;
    const float* hr = h + bb * HD;
    if (bf) {
        float acc = bf2f(((const u16*)b)[o]);
        const u16* wr = (const u16*)w + o * HD;
        for (int k = 0; k < HD; k += 8) {
            uint4 wv = *(const uint4*)(wr + k);
            float wa[8];
            unpack8(wv, wa);
            #pragma unroll
            for (int j = 0; j < 8; ++j) acc = fmaf(hr[k + j], wa[j], acc);
        }
        ((u16*)out)[bb * 256 + o] = f2bf(acc);
    } else {
        float acc = ((const float*)b)[o];
        const float* wr = (const float*)w + o * HD;
        for (int k = 0; k < HD; k += 4) {
            float4 wv = *(const float4*)(wr + k);
            acc = fmaf(hr[k + 0], wv.x, acc);
            acc = fmaf(hr[k + 1], wv.y, acc);
            acc = fmaf(hr[k + 2], wv.z, acc);
            acc = fmaf(hr[k + 3], wv.w, acc);
        }
        ((float*)out)[bb * 256 + o] = acc;
    }
}

extern "C" void kernel_launch(void* const* d_in, const int* in_sizes, int n_in,
                              void* d_out, int out_size, void* d_ws, size_t ws_size,
                              hipStream_t stream) {
    const void* x    = d_in[0];
    const void* Wih0 = d_in[1];
    const void* Whh0 = d_in[2];
    const void* bih0 = d_in[3];
    const void* bhh0 = d_in[4];
    const void* Wih1 = d_in[5];
    const void* Whh1 = d_in[6];
    const void* bih1 = d_in[7];
    const void* bhh1 = d_in[8];
    const void* fcw  = d_in[9];
    const void* fcb  = d_in[10];

    char* ws = (char*)d_ws;
    const size_t HB = (size_t)BAT * HD * 4;        // 256 KB state buffer
    const size_t XB = (size_t)4 * HD * BAT * 4;    // 1 MB gate-partial buffer
    int*   flag     = (int*)ws;
    size_t ofs = 4096;
    float* h1buf[2] = { (float*)(ws + ofs), (float*)(ws + ofs + HB) }; ofs += 2 * HB;
    float* h2buf[2] = { (float*)(ws + ofs), (float*)(ws + ofs + HB) }; ofs += 2 * HB;
    float* c1       = (float*)(ws + ofs); ofs += HB;
    float* c2       = (float*)(ws + ofs); ofs += HB;
    float* xpbuf[2] = { (float*)(ws + ofs), (float*)(ws + ofs + XB) }; ofs += 2 * XB;
    float* p1buf[2] = { (float*)(ws + ofs), (float*)(ws + ofs + XB) }; ofs += 2 * XB;

    // zero flag + h1/h2/c1/c2 (xp/p1 are written before any read)
    size_t zneed  = 4096 + 6 * HB;
    size_t zbytes = (ws_size < zneed) ? ws_size : zneed;
    hipMemsetAsync(d_ws, 0, zbytes, stream);

    detect_dtype<<<1, 64, 0, stream>>>((const u16*)x, flag);

    // launch n runs: L0(n) [+xp(n+1)], P1ih(n-1), F1hh(n-2)
    for (int n = -1; n <= TT + 1; ++n) {
        lstm_mega<<<192, 512, 0, stream>>>(
            flag, n, x,
            Wih0, Whh0, bih0, bhh0, Wih1, Whh1, bih1, bhh1,
            c1, c2,
            h1buf[(n - 1) & 1], h1buf[n & 1],
            h2buf[(n - 1) & 1], h2buf[n & 1],
            xpbuf[n & 1], xpbuf[(n + 1) & 1],
            p1buf[n & 1], p1buf[(n - 1) & 1]);
    }
    fc_kernel<<<64, 256, 0, stream>>>(flag, h2buf[(TT + 1) & 1], fcw, fcb, d_out);
}